// Round 9
// baseline (204.533 us; speedup 1.0000x reference)
//
#include <hip/hip_runtime.h>
#include <hip/hip_bf16.h>

#define SEQ 2048
#define DMODEL 1024
#define NHEAD 16
#define HDIM 64
#define DPOS 64
#define BATCH 2

constexpr float EVENT_HORIZON = 1e-6f;
constexpr float MAX_FORCE = 50.0f;
constexpr float CURV = 0.15f;
constexpr float SHIFT = 40.0f;   // P = exp(min(f,50)-40) <= e^10: fp16-safe, ratio-invariant

typedef __attribute__((ext_vector_type(8))) short frag8;        // 8 bf16/ushort
typedef __attribute__((ext_vector_type(8))) _Float16 half8;     // 8 fp16
typedef __attribute__((ext_vector_type(2))) _Float16 half2t;    // 2 fp16
typedef __attribute__((ext_vector_type(4))) float frag4f;       // 4 fp32 (C/D)

union A8u { half8 v; half2t h[4]; };

__device__ inline short bfbits(float f) {
  __hip_bfloat16 h = __float2bfloat16(f);
  return *reinterpret_cast<short*>(&h);
}
__device__ inline float bf2f(unsigned short u) {
  unsigned v = ((unsigned)u) << 16;
  union { unsigned u; float f; } c; c.u = v; return c.f;
}
__device__ inline half2t pkrtz(float a, float b) {
  return __builtin_bit_cast(half2t, __builtin_amdgcn_cvt_pkrtz(a, b));
}
// XOR swizzle in 16B units: row = 8 units (128B); b128 frag reads (fixed unit,
// 16 consecutive rows) and staging writes both cover banks <=2-way (free).
__device__ inline int swz(int row, int u) { return row * 8 + (u ^ (row & 7)); }

// ---------------------------------------------------------------------------
// Prep A: transpose x -> xt[bh][d][j] fp16.
// ---------------------------------------------------------------------------
__global__ __launch_bounds__(256) void prep_xt(
    const float* __restrict__ x, _Float16* __restrict__ xt) {
  int bh = blockIdx.x;           // b*16+h
  int h = bh & 15, b = bh >> 4;
  int t = threadIdx.x;
  int d = t & 63;
  int jg = (t >> 6) + (blockIdx.y << 2);   // j-group of 8, 0..255
  int j0 = jg * 8;
  const float* src = x + (size_t)(b * SEQ) * DMODEL + h * HDIM + d;
  half8 v;
#pragma unroll
  for (int jj = 0; jj < 8; ++jj)
    v[jj] = (_Float16)src[(size_t)(j0 + jj) * DMODEL];
  *(half8*)(xt + ((size_t)bh * HDIM + d) * SEQ + j0) = v;
}

// ---------------------------------------------------------------------------
// Prep B: Wout fp32 -> fp16.
// ---------------------------------------------------------------------------
__global__ __launch_bounds__(256) void prep_wh(
    const float* __restrict__ Wout, _Float16* __restrict__ wh) {
  int i = blockIdx.x * 256 + threadIdx.x;
  float4 v = ((const float4*)Wout)[i];
  _Float16 o[4] = {(_Float16)v.x, (_Float16)v.y, (_Float16)v.z, (_Float16)v.w};
  *(float2*)(wh + 4 * (size_t)i) = *(float2*)o;
}

// ---------------------------------------------------------------------------
// Kernel 1: masses[bh][s] = softplus( dot(x[b,s,h*64:+64], W_mass[h,:]) )
// ---------------------------------------------------------------------------
__global__ __launch_bounds__(256) void masses_kernel(
    const float* __restrict__ x, const float* __restrict__ Wm,
    float* __restrict__ masses) {
  int n = blockIdx.x * blockDim.x + threadIdx.x;
  if (n >= BATCH * NHEAD * SEQ) return;
  int s  = n & (SEQ - 1);
  int bh = n >> 11;
  int h  = bh & (NHEAD - 1);
  int b  = bh >> 4;
  const float* xp = x + ((size_t)(b * SEQ + s)) * DMODEL + h * HDIM;
  const float* wp = Wm + h * HDIM;
  float acc = 0.f;
#pragma unroll
  for (int d = 0; d < HDIM; ++d) acc += xp[d] * wp[d];
  masses[n] = (acc > 20.f) ? acc : log1pf(expf(acc));
}

// ---------------------------------------------------------------------------
// Kernel 2: LDS-tiled distance kernel, bf16 output (bf16 keeps the 1e6
// diagonal representable -> diagonal force clamps to exactly 50).
// ---------------------------------------------------------------------------
__global__ __launch_bounds__(256) void invdist_kernel(
    const float* __restrict__ pos, unsigned short* __restrict__ invd) {
  __shared__ float Li[64 * 68];
  __shared__ float Lj[64 * 68];
  int t = threadIdx.x;
  int i0 = blockIdx.y * 64, j0 = blockIdx.x * 64;

  int kk = (t & 15) * 4;
  int rr = t >> 4;
#pragma unroll
  for (int q = 0; q < 4; ++q) {
    int row = q * 16 + rr;
    float4 a = *(const float4*)(pos + (size_t)(i0 + row) * DPOS + kk);
    float4 b = *(const float4*)(pos + (size_t)(j0 + row) * DPOS + kk);
    Li[(kk + 0) * 68 + row] = a.x; Li[(kk + 1) * 68 + row] = a.y;
    Li[(kk + 2) * 68 + row] = a.z; Li[(kk + 3) * 68 + row] = a.w;
    Lj[(kk + 0) * 68 + row] = b.x; Lj[(kk + 1) * 68 + row] = b.y;
    Lj[(kk + 2) * 68 + row] = b.z; Lj[(kk + 3) * 68 + row] = b.w;
  }
  __syncthreads();

  int ti = (t >> 4) * 4;
  int tj = (t & 15) * 4;

  float acc[4][4];
#pragma unroll
  for (int a = 0; a < 4; ++a)
#pragma unroll
    for (int b = 0; b < 4; ++b) acc[a][b] = 0.f;

#pragma unroll 8
  for (int k = 0; k < 64; ++k) {
    float4 a = *(const float4*)(&Li[k * 68 + ti]);
    float4 b = *(const float4*)(&Lj[k * 68 + tj]);
    float av[4] = {a.x, a.y, a.z, a.w};
    float bv[4] = {b.x, b.y, b.z, b.w};
#pragma unroll
    for (int mi = 0; mi < 4; ++mi)
#pragma unroll
      for (int mj = 0; mj < 4; ++mj) {
        float d = av[mi] - bv[mj];
        acc[mi][mj] += d * d;
      }
  }

#pragma unroll
  for (int mi = 0; mi < 4; ++mi) {
    ushort4 o;
    unsigned short* op = (unsigned short*)&o;
#pragma unroll
    for (int mj = 0; mj < 4; ++mj) {
      float d2 = acc[mi][mj];
      float dn = sqrtf(d2 + EVENT_HORIZON);
      float w = d2 * (1.f + CURV * __cosf(dn));
      op[mj] = (unsigned short)bfbits(1.0f / fmaxf(w, EVENT_HORIZON));
    }
    *(ushort4*)(&invd[(size_t)(i0 + ti + mi) * SEQ + j0 + tj]) = o;
  }
}

// ---------------------------------------------------------------------------
// Kernel 3: fused gravitational attention, fp16 MFMA PV, swizzled LDS,
// DOUBLE-BUFFERED with register prefetch: ONE barrier per 64-j chunk.
// Iter c: issue loads for c+1 -> compute chunk c from buf[c&1] ->
// ds_write prefetch to buf[(c+1)&1] -> syncthreads. WAR hazard on the
// write buffer is covered by the PREVIOUS iteration's barrier.
// Block = 4 waves = 2 i-tiles x 2 j-half streams; epilogue combines halves.
// ---------------------------------------------------------------------------
__global__ __launch_bounds__(256, 5) void attn_mfma_kernel(
    const _Float16* __restrict__ xt, const float* __restrict__ masses,
    const unsigned short* __restrict__ invd, const float* __restrict__ G,
    _Float16* __restrict__ attnout) {
  __shared__ _Float16 Vs[2][2][64 * 64];   // [buf][stream], 32 KB

  int bh = blockIdx.x;
  int h = bh & (NHEAD - 1), b = bh >> 4;
  int ibase = blockIdx.y * 32;
  int t = threadIdx.x, w = t >> 6, lane = t & 63;
  int it = w >> 1, s = w & 1;
  int l15 = lane & 15, quad = lane >> 4;
  int iw = ibase + it * 16;

  float gabs = fabsf(G[h]);
  const float* mrow = masses + (size_t)bh * SEQ;
  float cm = gabs * mrow[iw + l15];                    // row scalar (i = iw+l15)
  const unsigned short* ivrow = invd + (size_t)(iw + l15) * SEQ + s * 1024;
  const float* mjb = mrow + s * 1024;

  // staging role within stream s (128 threads = waves {s, s+2}):
  int sid = it * 64 + lane;        // 0..127
  int srow = sid >> 1;             // d-row 0..63
  int sseg = (sid & 1) * 4;        // first 16B-unit (4 units each)
  const _Float16* srcrow =
      xt + ((size_t)bh * HDIM + srow) * SEQ + s * 1024 + sseg * 8;

  frag4f acc[4];
#pragma unroll
  for (int nt = 0; nt < 4; ++nt) acc[nt] = (frag4f)0.f;
  float sum = 0.f;

  // prologue: chunk 0 -> buf 0
  half8 p0 = *(const half8*)(srcrow);
  half8 p1 = *(const half8*)(srcrow + 8);
  half8 p2 = *(const half8*)(srcrow + 16);
  half8 p3 = *(const half8*)(srcrow + 24);
  {
    _Float16* wv = Vs[0][s];
    *(half8*)(wv + swz(srow, sseg + 0) * 8) = p0;
    *(half8*)(wv + swz(srow, sseg + 1) * 8) = p1;
    *(half8*)(wv + swz(srow, sseg + 2) * 8) = p2;
    *(half8*)(wv + swz(srow, sseg + 3) * 8) = p3;
  }
  __syncthreads();

  for (int c = 0; c < 16; ++c) {
    if (c < 15) {   // issue prefetch for chunk c+1 (latency hidden by compute)
      const _Float16* sp = srcrow + (c + 1) * 64;
      p0 = *(const half8*)(sp);
      p1 = *(const half8*)(sp + 8);
      p2 = *(const half8*)(sp + 16);
      p3 = *(const half8*)(sp + 24);
    }

    const _Float16* myVs = Vs[c & 1][s];
#pragma unroll
    for (int kh = 0; kh < 2; ++kh) {
      int jl = c * 64 + kh * 32 + quad * 8;
      float4 m0 = *(const float4*)(mjb + jl);
      float4 m1 = *(const float4*)(mjb + jl + 4);
      float mj[8] = {m0.x, m0.y, m0.z, m0.w, m1.x, m1.y, m1.z, m1.w};
      frag8 ivv = *(const frag8*)(ivrow + jl);

      float e[8];
#pragma unroll
      for (int jj = 0; jj < 8; ++jj) {
        float iv = bf2f((unsigned short)ivv[jj]);
        float f = fmaf(cm * mj[jj], iv, -SHIFT);
        e[jj] = __expf(fminf(f, MAX_FORCE - SHIFT));
        sum += e[jj];
      }
      A8u A;
#pragma unroll
      for (int p = 0; p < 4; ++p)
        A.h[p] = pkrtz(e[2 * p], e[2 * p + 1]);

#pragma unroll
      for (int nt = 0; nt < 4; ++nt) {
        half8 Bf = *(const half8*)(myVs + swz(nt * 16 + l15, kh * 4 + quad) * 8);
        acc[nt] = __builtin_amdgcn_mfma_f32_16x16x32_f16(A.v, Bf, acc[nt], 0, 0, 0);
      }
    }

    if (c < 15) {   // write prefetch into the other buffer
      _Float16* wv = Vs[(c + 1) & 1][s];
      *(half8*)(wv + swz(srow, sseg + 0) * 8) = p0;
      *(half8*)(wv + swz(srow, sseg + 1) * 8) = p1;
      *(half8*)(wv + swz(srow, sseg + 2) * 8) = p2;
      *(half8*)(wv + swz(srow, sseg + 3) * 8) = p3;
    }
    __syncthreads();
  }

  // row sums: lane L -> total for row (L&15) of this j-half
  sum += __shfl_xor(sum, 16, 64);
  sum += __shfl_xor(sum, 32, 64);

  // combine the two j-halves through LDS (reuse Vs; last barrier above)
  float* fb = (float*)&Vs[0][0][0];
  if (s == 1) {
#pragma unroll
    for (int nt = 0; nt < 4; ++nt)
#pragma unroll
      for (int reg = 0; reg < 4; ++reg)
        fb[it * 1088 + (quad * 4 + reg) * 64 + nt * 16 + l15] = acc[nt][reg];
    if (lane < 16) fb[it * 1088 + 1024 + lane] = sum;
  }
  __syncthreads();
  if (s == 0) {
#pragma unroll
    for (int reg = 0; reg < 4; ++reg) {
      int r = quad * 4 + reg;
      float stot = __shfl(sum, r) + fb[it * 1088 + 1024 + r];
      float inv = 1.f / stot;
#pragma unroll
      for (int nt = 0; nt < 4; ++nt) {
        float o = (acc[nt][reg] + fb[it * 1088 + r * 64 + nt * 16 + l15]) * inv;
        attnout[(size_t)(b * SEQ + iw + r) * DMODEL + h * HDIM + nt * 16 + l15] =
            (_Float16)o;
      }
    }
  }
}

// ---------------------------------------------------------------------------
// Kernel 4: out = attnout @ wh^T via fp16 MFMA. 128(M)x64(N) tile, BK=64,
// double-buffered swizzled LDS, one barrier per K-chunk. 4 waves, each
// 64m x 32n (4x2 frags). grid (16,32) = 512 blocks.
// ---------------------------------------------------------------------------
__global__ __launch_bounds__(256) void out_gemm_mfma(
    const _Float16* __restrict__ Ag, const _Float16* __restrict__ Wg,
    float* __restrict__ C) {
  __shared__ _Float16 As[2][128 * 64];   // 16 KB each
  __shared__ _Float16 Bs[2][64 * 64];    // 8 KB each

  int t = threadIdx.x, w = t >> 6, lane = t & 63;
  int l15 = lane & 15, quad = lane >> 4;
  int m0 = blockIdx.y * 128, n0 = blockIdx.x * 64;
  int mh = (w & 1) * 64, nh = (w >> 1) * 32;

  // staging: A row ar, 4 units (64B) at k-offset (t&1)*32; B row br, 2 units
  int ar = t >> 1;  int aku = (t & 1) * 4;   // unit base
  int br = t >> 2;  int bku = (t & 3) * 2;
  const _Float16* abase = Ag + (size_t)(m0 + ar) * DMODEL + aku * 8;
  const _Float16* bbase = Wg + (size_t)(n0 + br) * DMODEL + bku * 8;

  frag4f acc[4][2];
#pragma unroll
  for (int mt = 0; mt < 4; ++mt)
#pragma unroll
    for (int nt = 0; nt < 2; ++nt) acc[mt][nt] = (frag4f)0.f;

  half8 a0, a1, a2, a3, b0, b1;
  a0 = *(const half8*)(abase);      a1 = *(const half8*)(abase + 8);
  a2 = *(const half8*)(abase + 16); a3 = *(const half8*)(abase + 24);
  b0 = *(const half8*)(bbase);      b1 = *(const half8*)(bbase + 8);
  {
    _Float16* aw = As[0]; _Float16* bw = Bs[0];
    *(half8*)(aw + swz(ar, aku + 0) * 8) = a0;
    *(half8*)(aw + swz(ar, aku + 1) * 8) = a1;
    *(half8*)(aw + swz(ar, aku + 2) * 8) = a2;
    *(half8*)(aw + swz(ar, aku + 3) * 8) = a3;
    *(half8*)(bw + swz(br, bku + 0) * 8) = b0;
    *(half8*)(bw + swz(br, bku + 1) * 8) = b1;
  }
  __syncthreads();

  for (int kc = 0; kc < 16; ++kc) {
    if (kc < 15) {
      const _Float16* ap = abase + (kc + 1) * 64;
      const _Float16* bp = bbase + (kc + 1) * 64;
      a0 = *(const half8*)(ap);      a1 = *(const half8*)(ap + 8);
      a2 = *(const half8*)(ap + 16); a3 = *(const half8*)(ap + 24);
      b0 = *(const half8*)(bp);      b1 = *(const half8*)(bp + 8);
    }

    const _Float16* ac = As[kc & 1];
    const _Float16* bc = Bs[kc & 1];
#pragma unroll
    for (int kh = 0; kh < 2; ++kh) {
      half8 Af[4], Bf[2];
#pragma unroll
      for (int mt = 0; mt < 4; ++mt)
        Af[mt] = *(const half8*)(ac + swz(mh + mt * 16 + l15, kh * 4 + quad) * 8);
#pragma unroll
      for (int nt = 0; nt < 2; ++nt)
        Bf[nt] = *(const half8*)(bc + swz(nh + nt * 16 + l15, kh * 4 + quad) * 8);
#pragma unroll
      for (int mt = 0; mt < 4; ++mt)
#pragma unroll
        for (int nt = 0; nt < 2; ++nt)
          acc[mt][nt] = __builtin_amdgcn_mfma_f32_16x16x32_f16(Af[mt], Bf[nt], acc[mt][nt], 0, 0, 0);
    }

    if (kc < 15) {
      _Float16* aw = As[(kc + 1) & 1]; _Float16* bw = Bs[(kc + 1) & 1];
      *(half8*)(aw + swz(ar, aku + 0) * 8) = a0;
      *(half8*)(aw + swz(ar, aku + 1) * 8) = a1;
      *(half8*)(aw + swz(ar, aku + 2) * 8) = a2;
      *(half8*)(aw + swz(ar, aku + 3) * 8) = a3;
      *(half8*)(bw + swz(br, bku + 0) * 8) = b0;
      *(half8*)(bw + swz(br, bku + 1) * 8) = b1;
    }
    __syncthreads();
  }

#pragma unroll
  for (int mt = 0; mt < 4; ++mt)
#pragma unroll
    for (int nt = 0; nt < 2; ++nt)
#pragma unroll
      for (int reg = 0; reg < 4; ++reg) {
        int m = m0 + mh + mt * 16 + quad * 4 + reg;
        int n = n0 + nh + nt * 16 + l15;
        C[(size_t)m * DMODEL + n] = acc[mt][nt][reg];
      }
}

// ---------------------------------------------------------------------------
extern "C" void kernel_launch(void* const* d_in, const int* in_sizes, int n_in,
                              void* d_out, int out_size, void* d_ws, size_t ws_size,
                              hipStream_t stream) {
  const float* x    = (const float*)d_in[0];
  const float* pos  = (const float*)d_in[1];
  const float* Wm   = (const float*)d_in[2];
  const float* G    = (const float*)d_in[3];
  const float* Wout = (const float*)d_in[4];
  float* out = (float*)d_out;

  char* wsb = (char*)d_ws;
  float* masses = (float*)wsb;                                    // 256 KB
  unsigned short* invd = (unsigned short*)(wsb + (1 << 18));      // 8 MB
  _Float16* attnout = (_Float16*)(wsb + (1 << 18) + (8 << 20));   // 8 MB
  _Float16* xt      = (_Float16*)(wsb + (1 << 18) + (16 << 20));  // 8 MB
  _Float16* wh      = (_Float16*)(wsb + (1 << 18) + (24 << 20));  // 2 MB

  prep_xt<<<dim3(BATCH * NHEAD, 64), 256, 0, stream>>>(x, xt);
  prep_wh<<<(DMODEL * DMODEL / 4) / 256, 256, 0, stream>>>(Wout, wh);
  masses_kernel<<<(BATCH * NHEAD * SEQ) / 256, 256, 0, stream>>>(x, Wm, masses);
  invdist_kernel<<<dim3(SEQ / 64, SEQ / 64), 256, 0, stream>>>(pos, invd);
  attn_mfma_kernel<<<dim3(BATCH * NHEAD, SEQ / 32), 256, 0, stream>>>(
      xt, masses, invd, G, attnout);
  out_gemm_mfma<<<dim3(DMODEL / 64, (BATCH * SEQ) / 128), 256, 0, stream>>>(
      attnout, wh, out);
}

// Round 10
// 176.014 us; speedup vs baseline: 1.1620x; 1.1620x over previous
//
#include <hip/hip_runtime.h>
#include <hip/hip_bf16.h>

#define SEQ 2048
#define DMODEL 1024
#define NHEAD 16
#define HDIM 64
#define DPOS 64
#define BATCH 2

constexpr float EVENT_HORIZON = 1e-6f;
constexpr float MAX_FORCE = 50.0f;
constexpr float CURV = 0.15f;
constexpr float SHIFT = 40.0f;   // P = exp(min(f,50)-40) <= e^10: fp16-safe, ratio-invariant

typedef __attribute__((ext_vector_type(8))) short frag8;        // 8 bf16/ushort
typedef __attribute__((ext_vector_type(8))) _Float16 half8;     // 8 fp16
typedef __attribute__((ext_vector_type(2))) _Float16 half2t;    // 2 fp16
typedef __attribute__((ext_vector_type(4))) float frag4f;       // 4 fp32 (C/D)

union A8u { half8 v; half2t h[4]; };

__device__ inline short bfbits(float f) {
  __hip_bfloat16 h = __float2bfloat16(f);
  return *reinterpret_cast<short*>(&h);
}
__device__ inline float bf2f(unsigned short u) {
  unsigned v = ((unsigned)u) << 16;
  union { unsigned u; float f; } c; c.u = v; return c.f;
}
__device__ inline half2t pkrtz(float a, float b) {
  return __builtin_bit_cast(half2t, __builtin_amdgcn_cvt_pkrtz(a, b));
}
// XOR swizzle in 16B units: row = 8 units (128B); b128 frag reads (fixed unit,
// 16 consecutive rows) and staging writes both cover banks <=2-way (free).
__device__ inline int swz(int row, int u) { return row * 8 + (u ^ (row & 7)); }

// ---------------------------------------------------------------------------
// Prep A: transpose x -> xt[bh][d][j] fp16.
// ---------------------------------------------------------------------------
__global__ __launch_bounds__(256) void prep_xt(
    const float* __restrict__ x, _Float16* __restrict__ xt) {
  int bh = blockIdx.x;           // b*16+h
  int h = bh & 15, b = bh >> 4;
  int t = threadIdx.x;
  int d = t & 63;
  int jg = (t >> 6) + (blockIdx.y << 2);   // j-group of 8, 0..255
  int j0 = jg * 8;
  const float* src = x + (size_t)(b * SEQ) * DMODEL + h * HDIM + d;
  half8 v;
#pragma unroll
  for (int jj = 0; jj < 8; ++jj)
    v[jj] = (_Float16)src[(size_t)(j0 + jj) * DMODEL];
  *(half8*)(xt + ((size_t)bh * HDIM + d) * SEQ + j0) = v;
}

// ---------------------------------------------------------------------------
// Prep B: Wout fp32 -> fp16.
// ---------------------------------------------------------------------------
__global__ __launch_bounds__(256) void prep_wh(
    const float* __restrict__ Wout, _Float16* __restrict__ wh) {
  int i = blockIdx.x * 256 + threadIdx.x;
  float4 v = ((const float4*)Wout)[i];
  _Float16 o[4] = {(_Float16)v.x, (_Float16)v.y, (_Float16)v.z, (_Float16)v.w};
  *(float2*)(wh + 4 * (size_t)i) = *(float2*)o;
}

// ---------------------------------------------------------------------------
// Kernel 1: masses[bh][s] = softplus( dot(x[b,s,h*64:+64], W_mass[h,:]) )
// ---------------------------------------------------------------------------
__global__ __launch_bounds__(256) void masses_kernel(
    const float* __restrict__ x, const float* __restrict__ Wm,
    float* __restrict__ masses) {
  int n = blockIdx.x * blockDim.x + threadIdx.x;
  if (n >= BATCH * NHEAD * SEQ) return;
  int s  = n & (SEQ - 1);
  int bh = n >> 11;
  int h  = bh & (NHEAD - 1);
  int b  = bh >> 4;
  const float* xp = x + ((size_t)(b * SEQ + s)) * DMODEL + h * HDIM;
  const float* wp = Wm + h * HDIM;
  float acc = 0.f;
#pragma unroll
  for (int d = 0; d < HDIM; ++d) acc += xp[d] * wp[d];
  masses[n] = (acc > 20.f) ? acc : log1pf(expf(acc));
}

// ---------------------------------------------------------------------------
// Kernel 2: LDS-tiled distance kernel, bf16 output (bf16 keeps the 1e6
// diagonal representable -> diagonal force clamps to exactly 50).
// ---------------------------------------------------------------------------
__global__ __launch_bounds__(256) void invdist_kernel(
    const float* __restrict__ pos, unsigned short* __restrict__ invd) {
  __shared__ float Li[64 * 68];
  __shared__ float Lj[64 * 68];
  int t = threadIdx.x;
  int i0 = blockIdx.y * 64, j0 = blockIdx.x * 64;

  int kk = (t & 15) * 4;
  int rr = t >> 4;
#pragma unroll
  for (int q = 0; q < 4; ++q) {
    int row = q * 16 + rr;
    float4 a = *(const float4*)(pos + (size_t)(i0 + row) * DPOS + kk);
    float4 b = *(const float4*)(pos + (size_t)(j0 + row) * DPOS + kk);
    Li[(kk + 0) * 68 + row] = a.x; Li[(kk + 1) * 68 + row] = a.y;
    Li[(kk + 2) * 68 + row] = a.z; Li[(kk + 3) * 68 + row] = a.w;
    Lj[(kk + 0) * 68 + row] = b.x; Lj[(kk + 1) * 68 + row] = b.y;
    Lj[(kk + 2) * 68 + row] = b.z; Lj[(kk + 3) * 68 + row] = b.w;
  }
  __syncthreads();

  int ti = (t >> 4) * 4;
  int tj = (t & 15) * 4;

  float acc[4][4];
#pragma unroll
  for (int a = 0; a < 4; ++a)
#pragma unroll
    for (int b = 0; b < 4; ++b) acc[a][b] = 0.f;

#pragma unroll 8
  for (int k = 0; k < 64; ++k) {
    float4 a = *(const float4*)(&Li[k * 68 + ti]);
    float4 b = *(const float4*)(&Lj[k * 68 + tj]);
    float av[4] = {a.x, a.y, a.z, a.w};
    float bv[4] = {b.x, b.y, b.z, b.w};
#pragma unroll
    for (int mi = 0; mi < 4; ++mi)
#pragma unroll
      for (int mj = 0; mj < 4; ++mj) {
        float d = av[mi] - bv[mj];
        acc[mi][mj] += d * d;
      }
  }

#pragma unroll
  for (int mi = 0; mi < 4; ++mi) {
    ushort4 o;
    unsigned short* op = (unsigned short*)&o;
#pragma unroll
    for (int mj = 0; mj < 4; ++mj) {
      float d2 = acc[mi][mj];
      float dn = sqrtf(d2 + EVENT_HORIZON);
      float w = d2 * (1.f + CURV * __cosf(dn));
      op[mj] = (unsigned short)bfbits(1.0f / fmaxf(w, EVENT_HORIZON));
    }
    *(ushort4*)(&invd[(size_t)(i0 + ti + mi) * SEQ + j0 + tj]) = o;
  }
}

// ---------------------------------------------------------------------------
// Kernel 3: fused gravitational attention, fp16 MFMA PV.
// Block = 512 thr = 8 waves x 16 i-rows = 128 i-rows, ONE head, full-j sweep.
// grid (32 bh, 16) = 512 blocks. V-chunk (64j x 64d fp16, 8 KB) double-
// buffered in swizzled LDS: per chunk each thread does exactly 1 global b128
// + 1 ds_write b128; ONE barrier per chunk. Score inputs (invd row + masses)
// for chunk c+1 are REGISTER-prefetched at chunk c (the r9 gap: these loads
// were on the critical path).
// ---------------------------------------------------------------------------
__global__ __launch_bounds__(512, 4) void attn_mfma_kernel(
    const _Float16* __restrict__ xt, const float* __restrict__ masses,
    const unsigned short* __restrict__ invd, const float* __restrict__ G,
    _Float16* __restrict__ attnout) {
  __shared__ _Float16 Vs[2][64 * 64];   // [buf], 8 KB each, XOR-swizzled

  int bh = blockIdx.x;
  int h = bh & (NHEAD - 1), b = bh >> 4;
  int i0 = blockIdx.y * 128;
  int t = threadIdx.x, w = t >> 6, lane = t & 63;
  int l15 = lane & 15, quad = lane >> 4;
  int iw = i0 + w * 16;

  float gabs = fabsf(G[h]);
  const float* mrow = masses + (size_t)bh * SEQ;
  float cm = gabs * mrow[iw + l15];                 // row scalar (i = iw+l15)
  const unsigned short* ivrow = invd + (size_t)(iw + l15) * SEQ;

  // staging role: thread t -> d-row t>>3, 16B-unit t&7
  int srow = t >> 3, sunit = t & 7;
  const _Float16* srcrow =
      xt + ((size_t)bh * HDIM + srow) * SEQ + sunit * 8;

  frag4f acc[4];
#pragma unroll
  for (int nt = 0; nt < 4; ++nt) acc[nt] = (frag4f)0.f;
  float sum = 0.f;

  // ---- prologue: chunk 0 ----
  {
    half8 v0 = *(const half8*)(srcrow);
    *(half8*)(&Vs[0][0] + swz(srow, sunit) * 8) = v0;
  }
  frag8 iv_cur[2];
  float4 mj_cur[4];
  iv_cur[0] = *(const frag8*)(ivrow + quad * 8);
  iv_cur[1] = *(const frag8*)(ivrow + 32 + quad * 8);
  mj_cur[0] = *(const float4*)(mrow + quad * 8);
  mj_cur[1] = *(const float4*)(mrow + quad * 8 + 4);
  mj_cur[2] = *(const float4*)(mrow + 32 + quad * 8);
  mj_cur[3] = *(const float4*)(mrow + 32 + quad * 8 + 4);
  __syncthreads();

  for (int c = 0; c < 32; ++c) {
    // ---- issue all prefetches for chunk c+1 (latency hidden by compute) ----
    half8 vpre;
    frag8 iv_nxt[2];
    float4 mj_nxt[4];
    if (c < 31) {
      int jn = (c + 1) * 64;
      vpre = *(const half8*)(srcrow + jn);
      iv_nxt[0] = *(const frag8*)(ivrow + jn + quad * 8);
      iv_nxt[1] = *(const frag8*)(ivrow + jn + 32 + quad * 8);
      mj_nxt[0] = *(const float4*)(mrow + jn + quad * 8);
      mj_nxt[1] = *(const float4*)(mrow + jn + quad * 8 + 4);
      mj_nxt[2] = *(const float4*)(mrow + jn + 32 + quad * 8);
      mj_nxt[3] = *(const float4*)(mrow + jn + 32 + quad * 8 + 4);
    }

    // ---- compute chunk c from buf[c&1] ----
    const _Float16* myVs = &Vs[c & 1][0];
#pragma unroll
    for (int kh = 0; kh < 2; ++kh) {
      float mj[8] = {mj_cur[kh * 2].x, mj_cur[kh * 2].y,
                     mj_cur[kh * 2].z, mj_cur[kh * 2].w,
                     mj_cur[kh * 2 + 1].x, mj_cur[kh * 2 + 1].y,
                     mj_cur[kh * 2 + 1].z, mj_cur[kh * 2 + 1].w};
      frag8 ivv = iv_cur[kh];

      float e[8];
#pragma unroll
      for (int jj = 0; jj < 8; ++jj) {
        float iv = bf2f((unsigned short)ivv[jj]);
        float f = fmaf(cm * mj[jj], iv, -SHIFT);
        e[jj] = __expf(fminf(f, MAX_FORCE - SHIFT));
        sum += e[jj];
      }
      A8u A;
#pragma unroll
      for (int p = 0; p < 4; ++p)
        A.h[p] = pkrtz(e[2 * p], e[2 * p + 1]);

#pragma unroll
      for (int nt = 0; nt < 4; ++nt) {
        half8 Bf = *(const half8*)(myVs + swz(nt * 16 + l15, kh * 4 + quad) * 8);
        acc[nt] = __builtin_amdgcn_mfma_f32_16x16x32_f16(A.v, Bf, acc[nt], 0, 0, 0);
      }
    }

    // ---- rotate prefetches in; write V prefetch to the other buffer ----
    if (c < 31) {
      *(half8*)(&Vs[(c + 1) & 1][0] + swz(srow, sunit) * 8) = vpre;
      iv_cur[0] = iv_nxt[0]; iv_cur[1] = iv_nxt[1];
      mj_cur[0] = mj_nxt[0]; mj_cur[1] = mj_nxt[1];
      mj_cur[2] = mj_nxt[2]; mj_cur[3] = mj_nxt[3];
    }
    __syncthreads();
  }

  // ---- row sums + normalize + store (wave owns complete rows) ----
  sum += __shfl_xor(sum, 16, 64);
  sum += __shfl_xor(sum, 32, 64);

#pragma unroll
  for (int reg = 0; reg < 4; ++reg) {
    int r = quad * 4 + reg;            // C/D row within 16x16 tile
    float s = 1.f / __shfl(sum, r);
#pragma unroll
    for (int nt = 0; nt < 4; ++nt) {
      attnout[(size_t)(b * SEQ + iw + r) * DMODEL + h * HDIM + nt * 16 + l15] =
          (_Float16)(acc[nt][reg] * s);
    }
  }
}

// ---------------------------------------------------------------------------
// Kernel 4: out = attnout @ wh^T via fp16 MFMA. 128(M)x64(N) tile, BK=64,
// double-buffered swizzled LDS, one barrier per K-chunk. 4 waves, each
// 64m x 32n (4x2 frags). grid (16,32) = 512 blocks.
// ---------------------------------------------------------------------------
__global__ __launch_bounds__(256) void out_gemm_mfma(
    const _Float16* __restrict__ Ag, const _Float16* __restrict__ Wg,
    float* __restrict__ C) {
  __shared__ _Float16 As[2][128 * 64];   // 16 KB each
  __shared__ _Float16 Bs[2][64 * 64];    // 8 KB each

  int t = threadIdx.x, w = t >> 6, lane = t & 63;
  int l15 = lane & 15, quad = lane >> 4;
  int m0 = blockIdx.y * 128, n0 = blockIdx.x * 64;
  int mh = (w & 1) * 64, nh = (w >> 1) * 32;

  int ar = t >> 1;  int aku = (t & 1) * 4;
  int br = t >> 2;  int bku = (t & 3) * 2;
  const _Float16* abase = Ag + (size_t)(m0 + ar) * DMODEL + aku * 8;
  const _Float16* bbase = Wg + (size_t)(n0 + br) * DMODEL + bku * 8;

  frag4f acc[4][2];
#pragma unroll
  for (int mt = 0; mt < 4; ++mt)
#pragma unroll
    for (int nt = 0; nt < 2; ++nt) acc[mt][nt] = (frag4f)0.f;

  half8 a0, a1, a2, a3, b0, b1;
  a0 = *(const half8*)(abase);      a1 = *(const half8*)(abase + 8);
  a2 = *(const half8*)(abase + 16); a3 = *(const half8*)(abase + 24);
  b0 = *(const half8*)(bbase);      b1 = *(const half8*)(bbase + 8);
  {
    _Float16* aw = As[0]; _Float16* bw = Bs[0];
    *(half8*)(aw + swz(ar, aku + 0) * 8) = a0;
    *(half8*)(aw + swz(ar, aku + 1) * 8) = a1;
    *(half8*)(aw + swz(ar, aku + 2) * 8) = a2;
    *(half8*)(aw + swz(ar, aku + 3) * 8) = a3;
    *(half8*)(bw + swz(br, bku + 0) * 8) = b0;
    *(half8*)(bw + swz(br, bku + 1) * 8) = b1;
  }
  __syncthreads();

  for (int kc = 0; kc < 16; ++kc) {
    if (kc < 15) {
      const _Float16* ap = abase + (kc + 1) * 64;
      const _Float16* bp = bbase + (kc + 1) * 64;
      a0 = *(const half8*)(ap);      a1 = *(const half8*)(ap + 8);
      a2 = *(const half8*)(ap + 16); a3 = *(const half8*)(ap + 24);
      b0 = *(const half8*)(bp);      b1 = *(const half8*)(bp + 8);
    }

    const _Float16* ac = As[kc & 1];
    const _Float16* bc = Bs[kc & 1];
#pragma unroll
    for (int kh = 0; kh < 2; ++kh) {
      half8 Af[4], Bf[2];
#pragma unroll
      for (int mt = 0; mt < 4; ++mt)
        Af[mt] = *(const half8*)(ac + swz(mh + mt * 16 + l15, kh * 4 + quad) * 8);
#pragma unroll
      for (int nt = 0; nt < 2; ++nt)
        Bf[nt] = *(const half8*)(bc + swz(nh + nt * 16 + l15, kh * 4 + quad) * 8);
#pragma unroll
      for (int mt = 0; mt < 4; ++mt)
#pragma unroll
        for (int nt = 0; nt < 2; ++nt)
          acc[mt][nt] = __builtin_amdgcn_mfma_f32_16x16x32_f16(Af[mt], Bf[nt], acc[mt][nt], 0, 0, 0);
    }

    if (kc < 15) {
      _Float16* aw = As[(kc + 1) & 1]; _Float16* bw = Bs[(kc + 1) & 1];
      *(half8*)(aw + swz(ar, aku + 0) * 8) = a0;
      *(half8*)(aw + swz(ar, aku + 1) * 8) = a1;
      *(half8*)(aw + swz(ar, aku + 2) * 8) = a2;
      *(half8*)(aw + swz(ar, aku + 3) * 8) = a3;
      *(half8*)(bw + swz(br, bku + 0) * 8) = b0;
      *(half8*)(bw + swz(br, bku + 1) * 8) = b1;
    }
    __syncthreads();
  }

#pragma unroll
  for (int mt = 0; mt < 4; ++mt)
#pragma unroll
    for (int nt = 0; nt < 2; ++nt)
#pragma unroll
      for (int reg = 0; reg < 4; ++reg) {
        int m = m0 + mh + mt * 16 + quad * 4 + reg;
        int n = n0 + nh + nt * 16 + l15;
        C[(size_t)m * DMODEL + n] = acc[mt][nt][reg];
      }
}

// ---------------------------------------------------------------------------
extern "C" void kernel_launch(void* const* d_in, const int* in_sizes, int n_in,
                              void* d_out, int out_size, void* d_ws, size_t ws_size,
                              hipStream_t stream) {
  const float* x    = (const float*)d_in[0];
  const float* pos  = (const float*)d_in[1];
  const float* Wm   = (const float*)d_in[2];
  const float* G    = (const float*)d_in[3];
  const float* Wout = (const float*)d_in[4];
  float* out = (float*)d_out;

  char* wsb = (char*)d_ws;
  float* masses = (float*)wsb;                                    // 256 KB
  unsigned short* invd = (unsigned short*)(wsb + (1 << 18));      // 8 MB
  _Float16* attnout = (_Float16*)(wsb + (1 << 18) + (8 << 20));   // 8 MB
  _Float16* xt      = (_Float16*)(wsb + (1 << 18) + (16 << 20));  // 8 MB
  _Float16* wh      = (_Float16*)(wsb + (1 << 18) + (24 << 20));  // 2 MB

  prep_xt<<<dim3(BATCH * NHEAD, 64), 256, 0, stream>>>(x, xt);
  prep_wh<<<(DMODEL * DMODEL / 4) / 256, 256, 0, stream>>>(Wout, wh);
  masses_kernel<<<(BATCH * NHEAD * SEQ) / 256, 256, 0, stream>>>(x, Wm, masses);
  invdist_kernel<<<dim3(SEQ / 64, SEQ / 64), 256, 0, stream>>>(pos, invd);
  attn_mfma_kernel<<<dim3(BATCH * NHEAD, SEQ / 128), 512, 0, stream>>>(
      xt, masses, invd, G, attnout);
  out_gemm_mfma<<<dim3(DMODEL / 64, (BATCH * SEQ) / 128), 256, 0, stream>>>(
      attnout, wh, out);
}